// Round 6
// baseline (344.867 us; speedup 1.0000x reference)
//
#include <hip/hip_runtime.h>

typedef _Float16 f16x8 __attribute__((ext_vector_type(8)));
typedef float f32x16 __attribute__((ext_vector_type(16)));

#define CDIM 256
#define NE 1024
#define HW 4096        // H*W
#define CHW 1048576    // C*H*W
#define OUT_COS 262144 // 16*64*256
#define N_PIX 65536
#define NT 32          // 32-code tiles

// ws layout:
//   [0, 512K)      codebook hi fp16, TILED: t*8192 + f*512 + q*256 + n*8 + r
//                  code = t*32+n, dim = f*16 + q*8 + r   (f<16, q<2, r<8)
//   [512K, 516K)   0.5*||c||^2 fp32 (from fp64 sum)
//   [516K, 524K)   0.5*||c||^2 fp64 (for exact rescore)

__global__ void prep_kernel(const float* __restrict__ cb,
                            _Float16* __restrict__ hi,
                            float* __restrict__ c2f,
                            double* __restrict__ c2d) {
    int code = blockIdx.x;
    int lane = threadIdx.x; // 64 = 1 wave
    int t = code >> 5, n = code & 31;
    const float* row = cb + code * CDIM;
    double s = 0.0;
    #pragma unroll
    for (int i = 0; i < 4; ++i) {
        int d = i * 64 + lane;
        float x = row[d];
        s += (double)x * (double)x;
        int f = d >> 4, q = (d >> 3) & 1, rr = d & 7;
        hi[(size_t)t * 8192 + f * 512 + q * 256 + n * 8 + rr] = (_Float16)x;
    }
    #pragma unroll
    for (int off = 32; off > 0; off >>= 1)
        s += __shfl_down(s, off, 64);
    if (lane == 0) { c2f[code] = (float)(0.5 * s); c2d[code] = 0.5 * s; }
}

__device__ __forceinline__ void gl_lds16(const _Float16* g, _Float16* l) {
    __builtin_amdgcn_global_load_lds(
        (const __attribute__((address_space(1))) unsigned int*)g,
        (__attribute__((address_space(3))) unsigned int*)l, 16, 0, 0);
}

// Fused z+gt. Grid 1024: [0,512)->z, [512,1024)->gt. Block = 128 pixels,
// 4 waves x 32 pixels (32x32x16 MFMA).
// Phase 1: hi*hi screening only (16 MFMA + 16 ds_read per 32-code tile).
//   Per-lane best-2 as packed int keys: (score & ~0x3FF) | code_idx.
//   Screen err sigma ~3e-3 << typical top-2 gap ~8.
// Phase 2: per pixel, extract top-4 candidate codes cross-lane, rescore
//   exactly (original fp32 x & cb, fp64 accumulate) - final argmin is
//   MORE accurate than a full fp32 pass.
__launch_bounds__(256, 3)
__global__ void argmin_kernel(const float* __restrict__ Z,
                              const float* __restrict__ GT,
                              const _Float16* __restrict__ ghi,
                              const float* __restrict__ cb,
                              const float* __restrict__ c2f,
                              const double* __restrict__ c2d,
                              float* __restrict__ out_z,
                              float* __restrict__ out_gt) {
    __shared__ __align__(16) _Float16 lbuf[2][8192]; // 2 x 16 KB hi tiles
    __shared__ int cand_lds[4][32][4];               // per-wave candidates
    const int wave = threadIdx.x >> 6;
    const int lane = threadIdx.x & 63;
    const int l31 = lane & 31;
    const int qh = lane >> 5; // 0/1
    const int half = blockIdx.x >> 9;
    const float* X = half ? GT : Z;
    float* out_idx = half ? out_gt : out_z;
    const int p0 = (blockIdx.x & 511) * 128;

    // ---- A: pixel m = l31 of this wave's 32; k = qh*8+j per 16-dim frag.
    // hi-only, NEGATED so acc = c2 - hh_dot directly.
    const int p = p0 + wave * 32 + l31;
    const float* xbase = X + (size_t)(p >> 12) * CHW + (p & 4095);
    f16x8 nah[16];
    #pragma unroll
    for (int f = 0; f < 16; ++f) {
        #pragma unroll
        for (int j = 0; j < 8; ++j) {
            int d = f * 16 + qh * 8 + j;
            nah[f][j] = -(_Float16)xbase[(size_t)d * HW];
        }
    }

    int b1[16], b2[16];
    #pragma unroll
    for (int r = 0; r < 16; ++r) { b1[r] = 0x7fffffff; b2[r] = 0x7fffffff; }

    auto stage = [&](int b, int t) {
        #pragma unroll
        for (int i = 0; i < 4; ++i) {
            const int f = wave * 4 + i;
            gl_lds16(ghi + (size_t)t * 8192 + f * 512 + lane * 8, &lbuf[b][f * 512]);
        }
    };

    stage(0, 0);
    __syncthreads();

    for (int t = 0; t < NT; ++t) {
        const int cur = t & 1;
        if (t < NT - 1) stage(cur ^ 1, t + 1);

        const float c2 = c2f[t * 32 + l31];
        f32x16 accA, accB;
        #pragma unroll
        for (int r = 0; r < 16; ++r) { accA[r] = c2; accB[r] = 0.f; }

        #pragma unroll
        for (int f = 0; f < 16; f += 2) { // 2 chains for dep-latency
            f16x8 bh0 = *(const f16x8*)&lbuf[cur][f * 512 + lane * 8];
            f16x8 bh1 = *(const f16x8*)&lbuf[cur][(f + 1) * 512 + lane * 8];
            accA = __builtin_amdgcn_mfma_f32_32x32x16_f16(nah[f], bh0, accA, 0, 0, 0);
            accB = __builtin_amdgcn_mfma_f32_32x32x16_f16(nah[f + 1], bh1, accB, 0, 0, 0);
        }

        const int nbase = t * 32 + l31; // this lane's code (column)
        #pragma unroll
        for (int r = 0; r < 16; ++r) {
            float s = accA[r] + accB[r]; // = c2 - hh_dot  (>0, see analysis)
            int key = (__float_as_int(s) & 0xFFFFFC00) | nbase;
            int mx = max(b1[r], key);
            b1[r] = min(b1[r], key);
            b2[r] = min(b2[r], mx);
        }
        __syncthreads();
    }

    // ---- top-4 extraction per C-row (32-lane half holds the 32 columns) --
    #pragma unroll
    for (int r = 0; r < 16; ++r) {
        int x1 = b1[r], x2 = b2[r];
        int cands[4];
        #pragma unroll
        for (int k = 0; k < 4; ++k) {
            int m = x1;
            #pragma unroll
            for (int off = 16; off > 0; off >>= 1)
                m = min(m, __shfl_xor(m, off, 64));
            cands[k] = m;
            if (x1 == m) { x1 = x2; x2 = 0x7fffffff; } // keys globally unique
        }
        const int row = (r & 3) + 8 * (r >> 2) + 4 * qh; // C/D row mapping
        if (l31 == 0) {
            #pragma unroll
            for (int k = 0; k < 4; ++k)
                cand_lds[wave][row][k] = cands[k] & 1023;
        }
    }

    // ---- exact rescore: lane -> pixel l31, qh -> dim half; fp64 acc ----
    int c[4];
    #pragma unroll
    for (int k = 0; k < 4; ++k) c[k] = cand_lds[wave][l31][k];

    const int pr = p0 + wave * 32 + l31;
    const float* xb = X + (size_t)(pr >> 12) * CHW + (pr & 4095)
                        + (size_t)(qh * 128) * HW;
    double dot[4] = {0.0, 0.0, 0.0, 0.0};
    #pragma unroll 4
    for (int i4 = 0; i4 < 32; ++i4) {
        float x0 = xb[(size_t)(i4 * 4 + 0) * HW];
        float x1v = xb[(size_t)(i4 * 4 + 1) * HW];
        float x2v = xb[(size_t)(i4 * 4 + 2) * HW];
        float x3v = xb[(size_t)(i4 * 4 + 3) * HW];
        #pragma unroll
        for (int k = 0; k < 4; ++k) {
            const float4 v = *(const float4*)(cb + (size_t)c[k] * CDIM + qh * 128 + i4 * 4);
            dot[k] += (double)x0 * (double)v.x + (double)x1v * (double)v.y
                    + (double)x2v * (double)v.z + (double)x3v * (double)v.w;
        }
    }
    #pragma unroll
    for (int k = 0; k < 4; ++k)
        dot[k] += __shfl_xor(dot[k], 32, 64);

    if (qh == 0) {
        double bd = 1e300; int bi = 0x7fffffff;
        #pragma unroll
        for (int k = 0; k < 4; ++k) {
            double dk = c2d[c[k]] - dot[k];
            if (dk < bd || (dk == bd && c[k] < bi)) { bd = dk; bi = c[k]; }
        }
        out_idx[pr] = (float)bi;
    }
}

// cosine over H: one block per (b,w), one thread per channel c.
__global__ void cosine_kernel(const float* __restrict__ cb,
                              const float* __restrict__ idx_z_f,
                              const float* __restrict__ idx_gt_f,
                              float* __restrict__ out_cos) {
    __shared__ int s_ig[64], s_iq[64];
    const int bw = blockIdx.x;
    const int c = threadIdx.x;
    const int b = bw >> 6, w = bw & 63;
    if (c < 64) {
        s_ig[c] = (int)idx_gt_f[b * 4096 + c * 64 + w];
    } else if (c < 128) {
        int h = c - 64;
        s_iq[h] = (int)idx_z_f[b * 4096 + h * 64 + w];
    }
    __syncthreads();
    float num = 0.f, sa = 0.f, sb = 0.f;
    #pragma unroll 1
    for (int h = 0; h < 64; h += 4) {
        float av[4], bv[4];
        #pragma unroll
        for (int u = 0; u < 4; ++u) {
            av[u] = cb[s_ig[h + u] * CDIM + c];
            bv[u] = cb[s_iq[h + u] * CDIM + c];
        }
        #pragma unroll
        for (int u = 0; u < 4; ++u) {
            num += av[u] * bv[u];
            sa += av[u] * av[u];
            sb += bv[u] * bv[u];
        }
    }
    const float nx = fmaxf(sqrtf(sa), 1e-8f);
    const float ny = fmaxf(sqrtf(sb), 1e-8f);
    out_cos[bw * CDIM + c] = num / (nx * ny);
}

extern "C" void kernel_launch(void* const* d_in, const int* in_sizes, int n_in,
                              void* d_out, int out_size, void* d_ws, size_t ws_size,
                              hipStream_t stream) {
    const float* z  = (const float*)d_in[0];
    const float* gt = (const float*)d_in[1];
    const float* cb = (const float*)d_in[2];
    float* out = (float*)d_out;

    _Float16* hi = (_Float16*)d_ws;
    float*  c2f = (float*)((char*)d_ws + 512 * 1024);
    double* c2d = (double*)((char*)d_ws + 516 * 1024);

    float* out_cos    = out;                   // (16,64,256)
    float* out_idx_gt = out + OUT_COS;         // (65536,1)
    float* out_idx_z  = out + OUT_COS + N_PIX; // (65536,1)

    prep_kernel<<<NE, 64, 0, stream>>>(cb, hi, c2f, c2d);
    argmin_kernel<<<1024, 256, 0, stream>>>(z, gt, hi, cb, c2f, c2d,
                                            out_idx_z, out_idx_gt);
    cosine_kernel<<<1024, 256, 0, stream>>>(cb, out_idx_z, out_idx_gt, out_cos);
}

// Round 7
// 283.927 us; speedup vs baseline: 1.2146x; 1.2146x over previous
//
#include <hip/hip_runtime.h>

typedef _Float16 f16x8 __attribute__((ext_vector_type(8)));
typedef float f32x16 __attribute__((ext_vector_type(16)));

#define CDIM 256
#define NE 1024
#define HW 4096        // H*W
#define CHW 1048576    // C*H*W
#define OUT_COS 262144 // 16*64*256
#define N_PIX 65536
#define NT 32          // 32-code tiles
#define TAU 0.1f       // margin gate (~14 sigma of screen error)

// ws layout:
//   [0, 512K)      codebook hi fp16, TILED: t*8192 + f*512 + q*256 + n*8 + r
//                  code = t*32+n, dim = f*16 + q*8 + r   (f<16, q<2, r<8)
//   [512K, 516K)   0.5*||c||^2 fp32
//   [516K, 524K)   0.5*||c||^2 fp64 (exact rescore)

__global__ void prep_kernel(const float* __restrict__ cb,
                            _Float16* __restrict__ hi,
                            float* __restrict__ c2f,
                            double* __restrict__ c2d) {
    int code = blockIdx.x;
    int lane = threadIdx.x; // 64 = 1 wave
    int t = code >> 5, n = code & 31;
    const float* row = cb + code * CDIM;
    double s = 0.0;
    #pragma unroll
    for (int i = 0; i < 4; ++i) {
        int d = i * 64 + lane;
        float x = row[d];
        s += (double)x * (double)x;
        int f = d >> 4, q = (d >> 3) & 1, rr = d & 7;
        hi[(size_t)t * 8192 + f * 512 + q * 256 + n * 8 + rr] = (_Float16)x;
    }
    #pragma unroll
    for (int off = 32; off > 0; off >>= 1)
        s += __shfl_down(s, off, 64);
    if (lane == 0) { c2f[code] = (float)(0.5 * s); c2d[code] = 0.5 * s; }
}

__device__ __forceinline__ void gl_lds16(const _Float16* g, _Float16* l) {
    __builtin_amdgcn_global_load_lds(
        (const __attribute__((address_space(1))) unsigned int*)g,
        (__attribute__((address_space(3))) unsigned int*)l, 16, 0, 0);
}

// Fused z+gt. Grid 512: [0,256)->z, [256,512)->gt. Block = 256 pixels,
// 4 waves x 64 pixels (two 32x32x16 A-tiles per wave -> each B ds_read
// feeds 2 MFMAs). Screen = hh-only MFMA; per-lane top-2 packed int keys
// (float bits | code idx; s>0 so int order == float order). Margin-gated
// sparse exact rescore (fp64) only where screen top-2 gap < TAU (~0.7%).
__launch_bounds__(256, 2)
__global__ void argmin_kernel(const float* __restrict__ Z,
                              const float* __restrict__ GT,
                              const _Float16* __restrict__ ghi,
                              const float* __restrict__ cb,
                              const float* __restrict__ c2f,
                              const double* __restrict__ c2d,
                              float* __restrict__ out_z,
                              float* __restrict__ out_gt) {
    __shared__ __align__(16) _Float16 lbuf[2][8192]; // 2 x 16 KB hi tiles
    __shared__ int cand_lds[4][64];                  // per-wave (i1|i2|flag)
    const int wave = threadIdx.x >> 6;
    const int lane = threadIdx.x & 63;
    const int l31 = lane & 31;
    const int qh = lane >> 5; // 0/1 -> k-half
    const int half = blockIdx.x >> 8;
    const float* X = half ? GT : Z;
    float* out_idx = half ? out_gt : out_z;
    const int p0 = (blockIdx.x & 255) * 256;

    // ---- A: tile g holds pixels p0 + wave*64 + g*32 + l31 (m=l31),
    // k = qh*8 + j per 16-dim frag f. NEGATED so acc = c2 - hh_dot.
    f16x8 nah[2][16];
    #pragma unroll
    for (int g = 0; g < 2; ++g) {
        const int p = p0 + wave * 64 + g * 32 + l31;
        const float* xbase = X + (size_t)(p >> 12) * CHW + (p & 4095);
        #pragma unroll
        for (int f = 0; f < 16; ++f) {
            #pragma unroll
            for (int j = 0; j < 8; ++j) {
                int d = f * 16 + qh * 8 + j;
                nah[g][f][j] = -(_Float16)xbase[(size_t)d * HW];
            }
        }
    }

    int b1[2][16], b2[2][16];
    #pragma unroll
    for (int g = 0; g < 2; ++g)
        #pragma unroll
        for (int r = 0; r < 16; ++r) { b1[g][r] = 0x7fffffff; b2[g][r] = 0x7fffffff; }

    // stage tile t: 16 KB = 16 x 1KB chunks, 4 per wave
    auto stage = [&](int b, int t) {
        #pragma unroll
        for (int i = 0; i < 4; ++i) {
            const int f = wave * 4 + i;
            gl_lds16(ghi + (size_t)t * 8192 + f * 512 + lane * 8, &lbuf[b][f * 512]);
        }
    };

    stage(0, 0);
    __syncthreads();

    for (int t = 0; t < NT; ++t) {
        const int cur = t & 1;
        if (t < NT - 1) stage(cur ^ 1, t + 1);

        const float c2 = c2f[t * 32 + l31];
        f32x16 acc0, acc1;
        #pragma unroll
        for (int r = 0; r < 16; ++r) { acc0[r] = c2; acc1[r] = c2; }

        #pragma unroll
        for (int f = 0; f < 16; ++f) {
            f16x8 bh = *(const f16x8*)&lbuf[cur][f * 512 + lane * 8];
            acc0 = __builtin_amdgcn_mfma_f32_32x32x16_f16(nah[0][f], bh, acc0, 0, 0, 0);
            acc1 = __builtin_amdgcn_mfma_f32_32x32x16_f16(nah[1][f], bh, acc1, 0, 0, 0);
        }

        const int n = t * 32 + l31; // this lane's code column
        #pragma unroll
        for (int r = 0; r < 16; ++r) {
            int k0 = (__float_as_int(acc0[r]) & 0xFFFFFC00) | n;
            int t0 = max(b1[0][r], k0);
            b2[0][r] = min(b2[0][r], t0);
            b1[0][r] = min(b1[0][r], k0);
            int k1 = (__float_as_int(acc1[r]) & 0xFFFFFC00) | n;
            int t1 = max(b1[1][r], k1);
            b2[1][r] = min(b2[1][r], t1);
            b1[1][r] = min(b1[1][r], k1);
        }
        __syncthreads();
    }

    // ---- cross-lane top-2 merge (32 lanes of this qh half = all codes) --
    #pragma unroll
    for (int g = 0; g < 2; ++g) {
        #pragma unroll
        for (int r = 0; r < 16; ++r) {
            int x1 = b1[g][r], x2 = b2[g][r];
            #pragma unroll
            for (int off = 16; off > 0; off >>= 1) {
                int o1 = __shfl_xor(x1, off, 64);
                int o2 = __shfl_xor(x2, off, 64);
                int tt = max(x1, o1);
                x2 = min(min(x2, o2), tt);
                x1 = min(x1, o1);
            }
            if (l31 == 0) {
                const int i1 = x1 & 1023, i2 = x2 & 1023;
                const float s1 = __int_as_float(x1 & 0xFFFFFC00);
                const float s2 = __int_as_float(x2 & 0xFFFFFC00);
                const int row = (r & 3) + 8 * (r >> 2) + 4 * qh; // C/D row
                const int slot = g * 32 + row;
                const bool flag = (s2 - s1) < TAU;
                cand_lds[wave][slot] = i1 | (i2 << 10) | (flag ? (1 << 20) : 0);
                if (!flag) out_idx[p0 + wave * 64 + slot] = (float)i1;
            }
        }
    }

    // ---- sparse exact rescore: lane ℓ owns pixel wave*64 + ℓ ----
    const int info = cand_lds[wave][lane];
    if (info & (1 << 20)) {
        const int i1 = info & 1023, i2 = (info >> 10) & 1023;
        const int p = p0 + wave * 64 + lane;
        const float* xb = X + (size_t)(p >> 12) * CHW + (p & 4095);
        const float* r1 = cb + (size_t)i1 * CDIM;
        const float* r2 = cb + (size_t)i2 * CDIM;
        double d1 = 0.0, d2 = 0.0;
        #pragma unroll 4
        for (int d = 0; d < CDIM; d += 4) {
            float x0 = xb[(size_t)(d + 0) * HW];
            float x1v = xb[(size_t)(d + 1) * HW];
            float x2v = xb[(size_t)(d + 2) * HW];
            float x3v = xb[(size_t)(d + 3) * HW];
            const float4 v1 = *(const float4*)(r1 + d);
            const float4 v2 = *(const float4*)(r2 + d);
            d1 += (double)x0 * v1.x + (double)x1v * v1.y
                + (double)x2v * v1.z + (double)x3v * v1.w;
            d2 += (double)x0 * v2.x + (double)x1v * v2.y
                + (double)x2v * v2.z + (double)x3v * v2.w;
        }
        const double dd1 = c2d[i1] - d1;
        const double dd2 = c2d[i2] - d2;
        const int bi = (dd2 < dd1 || (dd2 == dd1 && i2 < i1)) ? i2 : i1;
        out_idx[p] = (float)bi;
    }
}

// cosine over H: one block per (b,w), one thread per channel c.
__global__ void cosine_kernel(const float* __restrict__ cb,
                              const float* __restrict__ idx_z_f,
                              const float* __restrict__ idx_gt_f,
                              float* __restrict__ out_cos) {
    __shared__ int s_ig[64], s_iq[64];
    const int bw = blockIdx.x;
    const int c = threadIdx.x;
    const int b = bw >> 6, w = bw & 63;
    if (c < 64) {
        s_ig[c] = (int)idx_gt_f[b * 4096 + c * 64 + w];
    } else if (c < 128) {
        int h = c - 64;
        s_iq[h] = (int)idx_z_f[b * 4096 + h * 64 + w];
    }
    __syncthreads();
    float num = 0.f, sa = 0.f, sb = 0.f;
    #pragma unroll 1
    for (int h = 0; h < 64; h += 4) {
        float av[4], bv[4];
        #pragma unroll
        for (int u = 0; u < 4; ++u) {
            av[u] = cb[s_ig[h + u] * CDIM + c];
            bv[u] = cb[s_iq[h + u] * CDIM + c];
        }
        #pragma unroll
        for (int u = 0; u < 4; ++u) {
            num += av[u] * bv[u];
            sa += av[u] * av[u];
            sb += bv[u] * bv[u];
        }
    }
    const float nx = fmaxf(sqrtf(sa), 1e-8f);
    const float ny = fmaxf(sqrtf(sb), 1e-8f);
    out_cos[bw * CDIM + c] = num / (nx * ny);
}

extern "C" void kernel_launch(void* const* d_in, const int* in_sizes, int n_in,
                              void* d_out, int out_size, void* d_ws, size_t ws_size,
                              hipStream_t stream) {
    const float* z  = (const float*)d_in[0];
    const float* gt = (const float*)d_in[1];
    const float* cb = (const float*)d_in[2];
    float* out = (float*)d_out;

    _Float16* hi = (_Float16*)d_ws;
    float*  c2f = (float*)((char*)d_ws + 512 * 1024);
    double* c2d = (double*)((char*)d_ws + 516 * 1024);

    float* out_cos    = out;                   // (16,64,256)
    float* out_idx_gt = out + OUT_COS;         // (65536,1)
    float* out_idx_z  = out + OUT_COS + N_PIX; // (65536,1)

    prep_kernel<<<NE, 64, 0, stream>>>(cb, hi, c2f, c2d);
    argmin_kernel<<<512, 256, 0, stream>>>(z, gt, hi, cb, c2f, c2d,
                                           out_idx_z, out_idx_gt);
    cosine_kernel<<<1024, 256, 0, stream>>>(cb, out_idx_z, out_idx_gt, out_cos);
}

// Round 8
// 251.040 us; speedup vs baseline: 1.3737x; 1.1310x over previous
//
#include <hip/hip_runtime.h>

typedef _Float16 f16x8 __attribute__((ext_vector_type(8)));
typedef float f32x4 __attribute__((ext_vector_type(4)));

#define CDIM 256
#define NE 1024
#define HW 4096        // H*W
#define CHW 1048576    // C*H*W
#define OUT_COS 262144 // 16*64*256
#define N_PIX 65536
#define NT 32          // 32-code LDS tiles (2 x 16-code subtiles)
#define TAU 0.1f       // margin gate (~14 sigma of screen+quant error)

// ws layout:
//   [0, 512K)      codebook hi fp16, TILED for 16x16x32 B-frags:
//                  addr = t*8192 + sub*4096 + f*512 + q*128 + n*8 + r
//                  code = t*32 + sub*16 + n, dim = f*32 + q*8 + r
//                  (t<32, sub<2, f<8, q<4, n<16, r<8)
//   [512K, 516K)   0.5*||c||^2 fp32
//   [516K, 524K)   0.5*||c||^2 fp64 (exact rescore)

__global__ void prep_kernel(const float* __restrict__ cb,
                            _Float16* __restrict__ hi,
                            float* __restrict__ c2f,
                            double* __restrict__ c2d) {
    int code = blockIdx.x;
    int lane = threadIdx.x; // 64 = 1 wave
    int t = code >> 5, sub = (code >> 4) & 1, n = code & 15;
    const float* row = cb + code * CDIM;
    double s = 0.0;
    #pragma unroll
    for (int i = 0; i < 4; ++i) {
        int d = i * 64 + lane;
        float x = row[d];
        s += (double)x * (double)x;
        int f = d >> 5, q = (d >> 3) & 3, r = d & 7;
        hi[(size_t)t * 8192 + sub * 4096 + f * 512 + q * 128 + n * 8 + r] =
            (_Float16)x;
    }
    #pragma unroll
    for (int off = 32; off > 0; off >>= 1)
        s += __shfl_down(s, off, 64);
    if (lane == 0) { c2f[code] = (float)(0.5 * s); c2d[code] = 0.5 * s; }
}

__device__ __forceinline__ void gl_lds16(const _Float16* g, _Float16* l) {
    __builtin_amdgcn_global_load_lds(
        (const __attribute__((address_space(1))) unsigned int*)g,
        (__attribute__((address_space(3))) unsigned int*)l, 16, 0, 0);
}

// Fused z+gt. Grid 512: [0,256)->z, [256,512)->gt. Block = 256 pixels,
// 4 waves x 64 pixels as FOUR 16x16x32 A-tiles (each B ds_read feeds 4
// MFMAs; keys only 32 regs since C/D is 4 regs/lane -> no spill, unlike
// R7's 32x32 variant). Screen = hh-only; per-lane top-2 packed int keys
// (float bits & ~0x3FF | code; s>0 so int order == float order).
// Margin-gated sparse exact rescore (fp64) where top-2 gap < TAU (~0.7%).
__launch_bounds__(256, 2)
__global__ void argmin_kernel(const float* __restrict__ Z,
                              const float* __restrict__ GT,
                              const _Float16* __restrict__ ghi,
                              const float* __restrict__ cb,
                              const float* __restrict__ c2f,
                              const double* __restrict__ c2d,
                              float* __restrict__ out_z,
                              float* __restrict__ out_gt) {
    __shared__ __align__(16) _Float16 lbuf[2][8192]; // 2 x 16 KB tiles
    __shared__ int cand_lds[4][64];                  // per-wave (i1|i2|flag)
    const int wave = threadIdx.x >> 6;
    const int lane = threadIdx.x & 63;
    const int l15 = lane & 15;
    const int quad = lane >> 4;
    const int half = blockIdx.x >> 8;
    const float* X = half ? GT : Z;
    float* out_idx = half ? out_gt : out_z;
    const int p0 = (blockIdx.x & 255) * 256;

    // ---- A: px-tile g holds pixels p0 + wave*64 + g*16 + l15 (m=l15),
    // k = quad*8 + j per 32-dim frag f (verified R1 A-layout). NEGATED so
    // acc = c2 - hh_dot directly.
    f16x8 nah[4][8];
    #pragma unroll
    for (int g = 0; g < 4; ++g) {
        const int p = p0 + wave * 64 + g * 16 + l15;
        const float* xbase = X + (size_t)(p >> 12) * CHW + (p & 4095);
        #pragma unroll
        for (int f = 0; f < 8; ++f) {
            #pragma unroll
            for (int j = 0; j < 8; ++j) {
                int d = f * 32 + quad * 8 + j;
                nah[g][f][j] = -(_Float16)xbase[(size_t)d * HW];
            }
        }
    }

    int b1[4][4], b2[4][4];
    #pragma unroll
    for (int g = 0; g < 4; ++g)
        #pragma unroll
        for (int r = 0; r < 4; ++r) { b1[g][r] = 0x7fffffff; b2[g][r] = 0x7fffffff; }

    // stage 16 KB tile = 16 x 1KB chunks, 4 per wave
    auto stage = [&](int b, int t) {
        #pragma unroll
        for (int i = 0; i < 4; ++i) {
            const int c = wave * 4 + i;
            gl_lds16(ghi + (size_t)t * 8192 + c * 512 + lane * 8, &lbuf[b][c * 512]);
        }
    };

    stage(0, 0);
    __syncthreads();

    for (int t = 0; t < NT; ++t) {
        const int cur = t & 1;
        if (t < NT - 1) stage(cur ^ 1, t + 1);

        #pragma unroll
        for (int sub = 0; sub < 2; ++sub) {
            const int n = t * 32 + sub * 16 + l15; // this lane's code (col)
            const float c2 = c2f[n];
            f32x4 acc[4];
            #pragma unroll
            for (int g = 0; g < 4; ++g)
                acc[g] = (f32x4){c2, c2, c2, c2};

            #pragma unroll
            for (int f = 0; f < 8; ++f) {
                // B[k=quad*8+j][n=l15]: contiguous 16B/lane, conflict-free
                f16x8 bh = *(const f16x8*)&lbuf[cur][sub * 4096 + f * 512 + lane * 8];
                acc[0] = __builtin_amdgcn_mfma_f32_16x16x32_f16(nah[0][f], bh, acc[0], 0, 0, 0);
                acc[1] = __builtin_amdgcn_mfma_f32_16x16x32_f16(nah[1][f], bh, acc[1], 0, 0, 0);
                acc[2] = __builtin_amdgcn_mfma_f32_16x16x32_f16(nah[2][f], bh, acc[2], 0, 0, 0);
                acc[3] = __builtin_amdgcn_mfma_f32_16x16x32_f16(nah[3][f], bh, acc[3], 0, 0, 0);
            }

            #pragma unroll
            for (int g = 0; g < 4; ++g) {
                #pragma unroll
                for (int r = 0; r < 4; ++r) {
                    int k = (__float_as_int(acc[g][r]) & 0xFFFFFC00) | n;
                    int mx = max(b1[g][r], k);      // before b1 update!
                    b2[g][r] = min(b2[g][r], mx);
                    b1[g][r] = min(b1[g][r], k);
                }
            }
        }
        __syncthreads();
    }

    // ---- cross-lane top-2 merge: 16 cols live in l15 of each quad ----
    #pragma unroll
    for (int g = 0; g < 4; ++g) {
        #pragma unroll
        for (int r = 0; r < 4; ++r) {
            int x1 = b1[g][r], x2 = b2[g][r];
            #pragma unroll
            for (int off = 8; off > 0; off >>= 1) { // stays in 16-lane group
                int o1 = __shfl_xor(x1, off, 64);
                int o2 = __shfl_xor(x2, off, 64);
                int tt = max(x1, o1);
                x2 = min(min(x2, o2), tt);
                x1 = min(x1, o1);
            }
            if (l15 == 0) {
                const int i1 = x1 & 1023, i2 = x2 & 1023;
                const float s1 = __int_as_float(x1 & 0xFFFFFC00);
                const float s2 = __int_as_float(x2 & 0xFFFFFC00);
                const int row = quad * 4 + r;       // 16x16 C/D row (m89/m91)
                const int slot = g * 16 + row;
                const bool flag = (s2 - s1) < TAU;
                cand_lds[wave][slot] = i1 | (i2 << 10) | (flag ? (1 << 20) : 0);
                if (!flag) out_idx[p0 + wave * 64 + slot] = (float)i1;
            }
        }
    }

    // ---- sparse exact rescore: lane ℓ owns pixel wave*64 + ℓ ----
    const int info = cand_lds[wave][lane];
    if (info & (1 << 20)) {
        const int i1 = info & 1023, i2 = (info >> 10) & 1023;
        const int p = p0 + wave * 64 + lane;
        const float* xb = X + (size_t)(p >> 12) * CHW + (p & 4095);
        const float* r1 = cb + (size_t)i1 * CDIM;
        const float* r2 = cb + (size_t)i2 * CDIM;
        double d1 = 0.0, d2 = 0.0;
        #pragma unroll 4
        for (int d = 0; d < CDIM; d += 4) {
            float x0 = xb[(size_t)(d + 0) * HW];
            float x1v = xb[(size_t)(d + 1) * HW];
            float x2v = xb[(size_t)(d + 2) * HW];
            float x3v = xb[(size_t)(d + 3) * HW];
            const float4 v1 = *(const float4*)(r1 + d);
            const float4 v2 = *(const float4*)(r2 + d);
            d1 += (double)x0 * v1.x + (double)x1v * v1.y
                + (double)x2v * v1.z + (double)x3v * v1.w;
            d2 += (double)x0 * v2.x + (double)x1v * v2.y
                + (double)x2v * v2.z + (double)x3v * v2.w;
        }
        const double dd1 = c2d[i1] - d1;
        const double dd2 = c2d[i2] - d2;
        const int bi = (dd2 < dd1 || (dd2 == dd1 && i2 < i1)) ? i2 : i1;
        out_idx[p] = (float)bi;
    }
}

// cosine over H: one block per (b,w), one thread per channel c.
__global__ void cosine_kernel(const float* __restrict__ cb,
                              const float* __restrict__ idx_z_f,
                              const float* __restrict__ idx_gt_f,
                              float* __restrict__ out_cos) {
    __shared__ int s_ig[64], s_iq[64];
    const int bw = blockIdx.x;
    const int c = threadIdx.x;
    const int b = bw >> 6, w = bw & 63;
    if (c < 64) {
        s_ig[c] = (int)idx_gt_f[b * 4096 + c * 64 + w];
    } else if (c < 128) {
        int h = c - 64;
        s_iq[h] = (int)idx_z_f[b * 4096 + h * 64 + w];
    }
    __syncthreads();
    float num = 0.f, sa = 0.f, sb = 0.f;
    #pragma unroll 1
    for (int h = 0; h < 64; h += 4) {
        float av[4], bv[4];
        #pragma unroll
        for (int u = 0; u < 4; ++u) {
            av[u] = cb[s_ig[h + u] * CDIM + c];
            bv[u] = cb[s_iq[h + u] * CDIM + c];
        }
        #pragma unroll
        for (int u = 0; u < 4; ++u) {
            num += av[u] * bv[u];
            sa += av[u] * av[u];
            sb += bv[u] * bv[u];
        }
    }
    const float nx = fmaxf(sqrtf(sa), 1e-8f);
    const float ny = fmaxf(sqrtf(sb), 1e-8f);
    out_cos[bw * CDIM + c] = num / (nx * ny);
}

extern "C" void kernel_launch(void* const* d_in, const int* in_sizes, int n_in,
                              void* d_out, int out_size, void* d_ws, size_t ws_size,
                              hipStream_t stream) {
    const float* z  = (const float*)d_in[0];
    const float* gt = (const float*)d_in[1];
    const float* cb = (const float*)d_in[2];
    float* out = (float*)d_out;

    _Float16* hi = (_Float16*)d_ws;
    float*  c2f = (float*)((char*)d_ws + 512 * 1024);
    double* c2d = (double*)((char*)d_ws + 516 * 1024);

    float* out_cos    = out;                   // (16,64,256)
    float* out_idx_gt = out + OUT_COS;         // (65536,1)
    float* out_idx_z  = out + OUT_COS + N_PIX; // (65536,1)

    prep_kernel<<<NE, 64, 0, stream>>>(cb, hi, c2f, c2d);
    argmin_kernel<<<512, 256, 0, stream>>>(z, gt, hi, cb, c2f, c2d,
                                           out_idx_z, out_idx_gt);
    cosine_kernel<<<1024, 256, 0, stream>>>(cb, out_idx_z, out_idx_gt, out_cos);
}